// Round 1
// baseline (253.045 us; speedup 1.0000x reference)
//
#include <hip/hip_runtime.h>

typedef __attribute__((ext_vector_type(4))) float  f32x4;
typedef __attribute__((ext_vector_type(4))) short  s16x4;
typedef __bf16 bf16x8 __attribute__((ext_vector_type(8)));

#define NBATCH 16
#define SEQ    4096
#define KIN    256
#define HY     64
#define HOUT   512
#define NROWS  (NBATCH*SEQ)   /* 65536 */
#define LC     32
#define NC     (SEQ/LC)       /* 128 */

static __device__ __forceinline__ short f2bf(float f) {
  unsigned u = __float_as_uint(f);
  u = u + 0x7FFF + ((u >> 16) & 1);          // RNE
  return (short)(u >> 16);
}
static __device__ __forceinline__ float bf2f(short h) {
  return __uint_as_float(((unsigned)(unsigned short)h) << 16);
}
static __device__ __forceinline__ f32x4 mfma16(bf16x8 a, bf16x8 b, f32x4 c) {
  return __builtin_amdgcn_mfma_f32_16x16x32_bf16(a, b, c, 0, 0, 0);
}
static __device__ __forceinline__ bf16x8 ldfrag(const short* p) {
  return *reinterpret_cast<const bf16x8*>(p);
}
static __device__ __forceinline__ float fsigmoid(float z) {
  return 1.f / (1.f + __expf(-z));
}

// ---------------- weight prep: fp32 -> bf16 (hi/lo split where precision matters)
__global__ void prep_w(const float* __restrict__ lin0W, const float* __restrict__ sig0W,
                       const float* __restrict__ fchW,  const float* __restrict__ fc2W,
                       short* __restrict__ W1h, short* __restrict__ W1l, short* __restrict__ W2h,
                       short* __restrict__ Fh,  short* __restrict__ Fl,  short* __restrict__ F2h) {
  int i = blockIdx.x * 256 + threadIdx.x;
  if (i < 16384) {
    float v = lin0W[i]; short h = f2bf(v);
    W1h[i] = h; W1l[i] = f2bf(v - bf2f(h));
    W2h[i] = f2bf(sig0W[i]);
  } else if (i < 16384 + 32768) {
    int j = i - 16384;
    float v = fchW[j]; short h = f2bf(v);
    Fh[j] = h; Fl[j] = f2bf(v - bf2f(h));
  } else if (i < 16384 + 32768 + 131072) {
    int j = i - 49152;
    F2h[j] = f2bf(fc2W[j]);
  }
}

// ---------------- g = relu( (x@lin0^T+b) * sigmoid(x@sig0^T+b) ), split-stored bf16
// wg: 256 thr (4 waves), 64 rows. wave w owns cols [16w,16w+16) of both y1,y2; rows 64 (4 row-tiles).
__global__ __launch_bounds__(256) void gemm_g(
    const float* __restrict__ x,
    const short* __restrict__ W1h, const short* __restrict__ W1l, const short* __restrict__ W2h,
    const float* __restrict__ lin0b, const float* __restrict__ sig0b,
    short* __restrict__ Gh, short* __restrict__ Gl) {
  __shared__ short Ah[64 * 256];
  __shared__ short Al[64 * 256];
  int tid = threadIdx.x;
  int row0 = blockIdx.x * 64;
  // stage x tile, converting fp32 -> bf16 hi/lo, XOR-swizzled rows
  #pragma unroll
  for (int i = 0; i < 16; ++i) {
    int f4 = tid + i * 256;
    int r = f4 >> 6;
    int k = (f4 & 63) << 2;
    f32x4 v = *reinterpret_cast<const f32x4*>(x + (size_t)(row0 + r) * KIN + k);
    s16x4 hh, ll;
    #pragma unroll
    for (int j = 0; j < 4; ++j) {
      short hb = f2bf(v[j]);
      hh[j] = hb;
      ll[j] = f2bf(v[j] - bf2f(hb));
    }
    int sidx = (r * 256 + k) ^ ((r & 7) << 3);
    *reinterpret_cast<s16x4*>(&Ah[sidx]) = hh;
    *reinterpret_cast<s16x4*>(&Al[sidx]) = ll;
  }
  __syncthreads();
  int w = tid >> 6, l = tid & 63;
  int lr = l & 15, lg = l >> 4;
  int c = w * 16 + lr;
  f32x4 acc1[4], acc2[4];
  #pragma unroll
  for (int rt = 0; rt < 4; ++rt) { acc1[rt] = (f32x4)0.f; acc2[rt] = (f32x4)0.f; }
  // y2 = x @ sig0^T (plain bf16)
  #pragma unroll
  for (int ks = 0; ks < 8; ++ks) {
    int kk = ks * 32 + lg * 8;
    bf16x8 b2 = ldfrag(W2h + c * 256 + kk);
    #pragma unroll
    for (int rt = 0; rt < 4; ++rt) {
      int r = rt * 16 + lr;
      bf16x8 a = ldfrag(&Ah[(r * 256 + kk) ^ ((r & 7) << 3)]);
      acc2[rt] = mfma16(a, b2, acc2[rt]);
    }
  }
  // y1 = x @ lin0^T (split: xh*Wh + xh*Wl + xl*Wh)
  #pragma unroll
  for (int ks = 0; ks < 8; ++ks) {
    int kk = ks * 32 + lg * 8;
    bf16x8 b1h = ldfrag(W1h + c * 256 + kk);
    bf16x8 b1l = ldfrag(W1l + c * 256 + kk);
    #pragma unroll
    for (int rt = 0; rt < 4; ++rt) {
      int r = rt * 16 + lr;
      int si = (r * 256 + kk) ^ ((r & 7) << 3);
      bf16x8 ah = ldfrag(&Ah[si]);
      bf16x8 al = ldfrag(&Al[si]);
      acc1[rt] = mfma16(ah, b1h, acc1[rt]);
      acc1[rt] = mfma16(ah, b1l, acc1[rt]);
      acc1[rt] = mfma16(al, b1h, acc1[rt]);
    }
  }
  float bl = lin0b[c], bs = sig0b[c];
  #pragma unroll
  for (int rt = 0; rt < 4; ++rt) {
    #pragma unroll
    for (int j = 0; j < 4; ++j) {
      int row = row0 + rt * 16 + lg * 4 + j;   // C/D: row=(l>>4)*4+reg, col=l&15 (m89)
      float y1 = acc1[rt][j] + bl;
      float y2 = acc2[rt][j] + bs;
      float g = y1 * fsigmoid(y2);
      g = g > 0.f ? g : 0.f;
      short gh = f2bf(g);
      Gh[(size_t)row * HY + c] = gh;
      Gl[(size_t)row * HY + c] = f2bf(g - bf2f(gh));
    }
  }
}

// ---------------- b = (g@fch^T + b) * sigmoid(x@fc2^T + b), fp32 -> d_out (in-place scan later)
// wg: 256 thr, 64 rows; wave w owns cols [128w,128w+128) as 8 col-tiles.
__global__ __launch_bounds__(256) void gemm_b(
    const float* __restrict__ x,
    const short* __restrict__ Gh, const short* __restrict__ Gl,
    const short* __restrict__ F2h, const short* __restrict__ Fh, const short* __restrict__ Fl,
    const float* __restrict__ fchb, const float* __restrict__ fc2b,
    float* __restrict__ bout) {
  __shared__ short Ax[64 * 256];
  __shared__ short SgH[64 * 64];
  __shared__ short SgL[64 * 64];
  int tid = threadIdx.x;
  int row0 = blockIdx.x * 64;
  #pragma unroll
  for (int i = 0; i < 16; ++i) {
    int f4 = tid + i * 256;
    int r = f4 >> 6, k = (f4 & 63) << 2;
    f32x4 v = *reinterpret_cast<const f32x4*>(x + (size_t)(row0 + r) * KIN + k);
    s16x4 hh;
    #pragma unroll
    for (int j = 0; j < 4; ++j) hh[j] = f2bf(v[j]);
    *reinterpret_cast<s16x4*>(&Ax[(r * 256 + k) ^ ((r & 7) << 3)]) = hh;
  }
  #pragma unroll
  for (int i = 0; i < 4; ++i) {
    int s4 = tid + i * 256;
    int r = s4 >> 4, k = (s4 & 15) << 2;
    s16x4 vh = *reinterpret_cast<const s16x4*>(Gh + (size_t)(row0 + r) * HY + k);
    s16x4 vl = *reinterpret_cast<const s16x4*>(Gl + (size_t)(row0 + r) * HY + k);
    int si = (r * 64 + k) ^ ((r & 7) << 3);
    *reinterpret_cast<s16x4*>(&SgH[si]) = vh;
    *reinterpret_cast<s16x4*>(&SgL[si]) = vl;
  }
  __syncthreads();
  int w = tid >> 6, l = tid & 63;
  int lr = l & 15, lg = l >> 4;
  for (int ct = 0; ct < 8; ++ct) {
    int c = w * 128 + ct * 16 + lr;
    f32x4 a2[4], af[4];
    #pragma unroll
    for (int rt = 0; rt < 4; ++rt) { a2[rt] = (f32x4)0.f; af[rt] = (f32x4)0.f; }
    #pragma unroll
    for (int ks = 0; ks < 8; ++ks) {          // fc2 (plain bf16, feeds sigmoid)
      int kk = ks * 32 + lg * 8;
      bf16x8 b = ldfrag(F2h + (size_t)c * 256 + kk);
      #pragma unroll
      for (int rt = 0; rt < 4; ++rt) {
        int r = rt * 16 + lr;
        bf16x8 a = ldfrag(&Ax[(r * 256 + kk) ^ ((r & 7) << 3)]);
        a2[rt] = mfma16(a, b, a2[rt]);
      }
    }
    #pragma unroll
    for (int ks = 0; ks < 2; ++ks) {          // fch (split-bf16, linear path)
      int kk = ks * 32 + lg * 8;
      bf16x8 bh = ldfrag(Fh + (size_t)c * 64 + kk);
      bf16x8 bl = ldfrag(Fl + (size_t)c * 64 + kk);
      #pragma unroll
      for (int rt = 0; rt < 4; ++rt) {
        int r = rt * 16 + lr;
        int si = (r * 64 + kk) ^ ((r & 7) << 3);
        bf16x8 gh = ldfrag(&SgH[si]);
        bf16x8 gl = ldfrag(&SgL[si]);
        af[rt] = mfma16(gh, bh, af[rt]);
        af[rt] = mfma16(gh, bl, af[rt]);
        af[rt] = mfma16(gl, bh, af[rt]);
      }
    }
    float bc = fchb[c], b2c = fc2b[c];
    #pragma unroll
    for (int rt = 0; rt < 4; ++rt) {
      #pragma unroll
      for (int j = 0; j < 4; ++j) {
        int row = row0 + rt * 16 + lg * 4 + j;
        float alpha = fsigmoid(a2[rt][j] + b2c);
        bout[(size_t)row * HOUT + c] = (af[rt][j] + bc) * alpha;
      }
    }
  }
}

// ---------------- scan pass A: per-chunk max-plus operator (C,S). 1 wave/wg, 8 ch/lane.
__global__ __launch_bounds__(64) void scan_passA(const float* __restrict__ bm,
                                                 float* __restrict__ Cc, float* __restrict__ Sc) {
  int bc = blockIdx.x;
  int batch = bc >> 7, chunk = bc & (NC - 1);
  int l = threadIdx.x;
  const float* bp = bm + ((size_t)batch * SEQ + chunk * LC) * HOUT + l * 8;
  f32x4 v0 = *reinterpret_cast<const f32x4*>(bp);
  f32x4 v1 = *reinterpret_cast<const f32x4*>(bp + 4);
  float C[8], S[8];
  #pragma unroll
  for (int i = 0; i < 4; ++i) { S[i] = v0[i]; S[4 + i] = v1[i]; C[i] = 0.f; C[4 + i] = 0.f; }
  for (int t = 1; t < LC; ++t) {
    const float* bt = bp + (size_t)t * HOUT;
    v0 = *reinterpret_cast<const f32x4*>(bt);
    v1 = *reinterpret_cast<const f32x4*>(bt + 4);
    float bb[8];
    #pragma unroll
    for (int i = 0; i < 4; ++i) { bb[i] = v0[i]; bb[4 + i] = v1[i]; }
    float pC = __shfl(C[7], (l + 63) & 63);
    float pS = __shfl(S[7], (l + 63) & 63);
    #pragma unroll
    for (int i = 7; i >= 1; --i) { C[i] = fmaxf(0.f, bb[i] + C[i - 1]); S[i] = bb[i] + S[i - 1]; }
    C[0] = fmaxf(0.f, bb[0] + pC);
    S[0] = bb[0] + pS;
  }
  float* cp = Cc + (size_t)bc * HOUT + l * 8;
  float* sp = Sc + (size_t)bc * HOUT + l * 8;
  #pragma unroll
  for (int i = 0; i < 8; ++i) { cp[i] = C[i]; sp[i] = S[i]; }
}

// ---------------- combine: sequential over chunks per batch; emits h_in per chunk + last.
__global__ __launch_bounds__(64) void scan_combine(const float* __restrict__ hidden,
                                                   const float* __restrict__ Cc, const float* __restrict__ Sc,
                                                   float* __restrict__ hIn, float* __restrict__ lastOut) {
  int batch = blockIdx.x;
  int l = threadIdx.x;
  float h[8];
  const float* hp = hidden + batch * HOUT + l * 8;
  #pragma unroll
  for (int i = 0; i < 8; ++i) h[i] = hp[i];
  size_t base0 = ((size_t)batch * NC) * HOUT + l * 8;
  // software-pipelined C/S loads
  f32x4 c0 = *reinterpret_cast<const f32x4*>(Cc + base0);
  f32x4 c1 = *reinterpret_cast<const f32x4*>(Cc + base0 + 4);
  f32x4 s0 = *reinterpret_cast<const f32x4*>(Sc + base0);
  f32x4 s1 = *reinterpret_cast<const f32x4*>(Sc + base0 + 4);
  for (int c = 0; c < NC; ++c) {
    size_t base = base0 + (size_t)c * HOUT;
    f32x4 nc0, nc1, ns0, ns1;
    if (c + 1 < NC) {
      size_t nb = base + HOUT;
      nc0 = *reinterpret_cast<const f32x4*>(Cc + nb);
      nc1 = *reinterpret_cast<const f32x4*>(Cc + nb + 4);
      ns0 = *reinterpret_cast<const f32x4*>(Sc + nb);
      ns1 = *reinterpret_cast<const f32x4*>(Sc + nb + 4);
    }
    #pragma unroll
    for (int i = 0; i < 8; ++i) hIn[base + i] = h[i];
    float hs[8];
    #pragma unroll
    for (int i = 0; i < 8; ++i) hs[i] = __shfl(h[i], (l + 64 - (LC / 8)) & 63); // d-LC
    #pragma unroll
    for (int i = 0; i < 4; ++i) {
      h[i]     = fmaxf(c0[i], s0[i] + hs[i]);
      h[4 + i] = fmaxf(c1[i], s1[i] + hs[4 + i]);
    }
    c0 = nc0; c1 = nc1; s0 = ns0; s1 = ns1;
  }
  float* lp = lastOut + batch * HOUT + l * 8;
  #pragma unroll
  for (int i = 0; i < 8; ++i) lp[i] = h[i];
}

// ---------------- pass B: replay recurrence within chunk, overwrite b with h in place.
__global__ __launch_bounds__(64) void scan_passB(float* __restrict__ bm, const float* __restrict__ hIn) {
  int bc = blockIdx.x;
  int batch = bc >> 7, chunk = bc & (NC - 1);
  int l = threadIdx.x;
  const float* hp = hIn + (size_t)bc * HOUT + l * 8;
  float h[8];
  #pragma unroll
  for (int i = 0; i < 8; ++i) h[i] = hp[i];
  float* bp = bm + ((size_t)batch * SEQ + chunk * LC) * HOUT + l * 8;
  for (int t = 0; t < LC; ++t) {
    float* bt = bp + (size_t)t * HOUT;
    f32x4 v0 = *reinterpret_cast<const f32x4*>(bt);
    f32x4 v1 = *reinterpret_cast<const f32x4*>(bt + 4);
    float bb[8];
    #pragma unroll
    for (int i = 0; i < 4; ++i) { bb[i] = v0[i]; bb[4 + i] = v1[i]; }
    float ph = __shfl(h[7], (l + 63) & 63);
    #pragma unroll
    for (int i = 7; i >= 1; --i) h[i] = fmaxf(0.f, bb[i] + h[i - 1]);
    h[0] = fmaxf(0.f, bb[0] + ph);
    f32x4 o0, o1;
    #pragma unroll
    for (int i = 0; i < 4; ++i) { o0[i] = h[i]; o1[i] = h[4 + i]; }
    *reinterpret_cast<f32x4*>(bt) = o0;
    *reinterpret_cast<f32x4*>(bt + 4) = o1;
  }
}

extern "C" void kernel_launch(void* const* d_in, const int* in_sizes, int n_in,
                              void* d_out, int out_size, void* d_ws, size_t ws_size,
                              hipStream_t stream) {
  (void)in_sizes; (void)n_in; (void)out_size; (void)ws_size;
  const float* x      = (const float*)d_in[0];
  const float* hidden = (const float*)d_in[1];
  const float* lin0W  = (const float*)d_in[2];
  const float* lin0b  = (const float*)d_in[3];
  const float* sig0W  = (const float*)d_in[4];
  const float* sig0b  = (const float*)d_in[5];
  const float* fchW   = (const float*)d_in[6];
  const float* fchb   = (const float*)d_in[7];
  const float* fc2W   = (const float*)d_in[8];
  const float* fc2b   = (const float*)d_in[9];
  float* outO  = (float*)d_out;
  float* lastO = outO + (size_t)NROWS * HOUT;

  char* wsb = (char*)d_ws;
  size_t off = 0;
  auto alloc = [&](size_t bytes) { char* p = wsb + off; off += (bytes + 255) & ~(size_t)255; return p; };
  float* Cc  = (float*)alloc((size_t)NBATCH * NC * HOUT * 4);
  float* Sc  = (float*)alloc((size_t)NBATCH * NC * HOUT * 4);
  float* hIn = (float*)alloc((size_t)NBATCH * NC * HOUT * 4);
  short* W1h = (short*)alloc(HY * KIN * 2);
  short* W1l = (short*)alloc(HY * KIN * 2);
  short* W2h = (short*)alloc(HY * KIN * 2);
  short* Fh  = (short*)alloc(HOUT * HY * 2);
  short* Fl  = (short*)alloc(HOUT * HY * 2);
  short* F2h = (short*)alloc(HOUT * KIN * 2);
  short* Gh  = (short*)alloc((size_t)NROWS * HY * 2);
  short* Gl  = (short*)alloc((size_t)NROWS * HY * 2);

  prep_w<<<704, 256, 0, stream>>>(lin0W, sig0W, fchW, fc2W, W1h, W1l, W2h, Fh, Fl, F2h);
  gemm_g<<<NROWS / 64, 256, 0, stream>>>(x, W1h, W1l, W2h, lin0b, sig0b, Gh, Gl);
  gemm_b<<<NROWS / 64, 256, 0, stream>>>(x, Gh, Gl, F2h, Fh, Fl, fchb, fc2b, outO);
  scan_passA<<<NBATCH * NC, 64, 0, stream>>>(outO, Cc, Sc);
  scan_combine<<<NBATCH, 64, 0, stream>>>(hidden, Cc, Sc, hIn, lastO);
  scan_passB<<<NBATCH * NC, 64, 0, stream>>>(outO, hIn);
}